// Round 1
// baseline (268.068 us; speedup 1.0000x reference)
//
#include <hip/hip_runtime.h>

#define B_TOT 4096
#define S_LEN 2048
#define AR_N  8
#define E_DIM 8
#define U_ROW (S_LEN + E_DIM)   // 2056 floats per batch row of u
#define O_ROW (S_LEN + AR_N + 1) // 2057 floats per batch row of out

// One thread per batch element. Recurrence rewritten in difference space:
//   d_t = sum_j w[j]*d_{t-8+j} + b_t,  b_t = sum_k w[8+k]*u[1+t+k],  x_t = x_{t-1} + d_t
// Loop-carried dep is a single FMA (w[7]*d_{t-1}) -> ~4 cyc/step chain, hidden.
__global__ __launch_bounds__(64, 1) void arix_kernel(
    const float* __restrict__ y,
    const float* __restrict__ u,
    const float* __restrict__ W,
    float* __restrict__ out)
{
    const int b = blockIdx.x * blockDim.x + threadIdx.x;
    if (b >= B_TOT) return;

    // Wave-uniform weights (uniform address -> s_load)
    float wd[8], wu[8];
#pragma unroll
    for (int j = 0; j < 8; ++j) { wd[j] = W[j]; wu[j] = W[8 + j]; }

    const float* yb = y + b * (AR_N + 1);
    const float* ub = u + (long)b * U_ROW;
    float*       ob = out + (long)b * O_ROW;

    // Copy initial window to output head, build initial diff ring and x.
    float yv[9];
#pragma unroll
    for (int j = 0; j < 9; ++j) { yv[j] = yb[j]; ob[j] = yv[j]; }

    float dr[8];           // dr[j] = d_{t-8+j}
#pragma unroll
    for (int j = 0; j < 8; ++j) dr[j] = yv[j + 1] - yv[j];
    float x = yv[8];

    // u window: ua[0..15] = u[t .. t+15]; step s needs u[t+s+1 .. t+s+8] = ua[s+1..s+8]
    float ua[16];
    {
        const float4* up = (const float4*)(ub);   // row base is 16B aligned (2056*4 % 16 == 0)
#pragma unroll
        for (int q = 0; q < 4; ++q) {
            float4 v = up[q];
            ua[4*q+0] = v.x; ua[4*q+1] = v.y; ua[4*q+2] = v.z; ua[4*q+3] = v.w;
        }
    }

    for (int t = 0; t < S_LEN; t += 8) {
        float xo[8];
#pragma unroll
        for (int s = 0; s < 8; ++s) {
            // exogenous dot (independent of chain)
            float acc = wu[0] * ua[s + 1];
#pragma unroll
            for (int k = 1; k < 8; ++k) acc = fmaf(wu[k], ua[s + 1 + k], acc);
            // AR part; j=7 (dep on previous step's acc) scheduled last
#pragma unroll
            for (int j = 0; j < 8; ++j) acc = fmaf(wd[j], dr[j], acc);
            // rotate diff ring (register renaming under full unroll)
#pragma unroll
            for (int j = 0; j < 7; ++j) dr[j] = dr[j + 1];
            dr[7] = acc;
            x += acc;
            xo[s] = x;
        }
#pragma unroll
        for (int s = 0; s < 8; ++s) ob[9 + t + s] = xo[s];

        // slide u window by 8, load next 8 (aligned float4 pair)
#pragma unroll
        for (int j = 0; j < 8; ++j) ua[j] = ua[j + 8];
        if (t + 8 < S_LEN) {
            const float4* up = (const float4*)(ub + t + 16);
            float4 v0 = up[0], v1 = up[1];
            ua[8]  = v0.x; ua[9]  = v0.y; ua[10] = v0.z; ua[11] = v0.w;
            ua[12] = v1.x; ua[13] = v1.y; ua[14] = v1.z; ua[15] = v1.w;
        }
    }
}

extern "C" void kernel_launch(void* const* d_in, const int* in_sizes, int n_in,
                              void* d_out, int out_size, void* d_ws, size_t ws_size,
                              hipStream_t stream) {
    const float* y = (const float*)d_in[0];
    const float* u = (const float*)d_in[1];
    const float* W = (const float*)d_in[2];
    float* out = (float*)d_out;

    dim3 grid(B_TOT / 64), block(64);
    arix_kernel<<<grid, block, 0, stream>>>(y, u, W, out);
}

// Round 2
// 159.370 us; speedup vs baseline: 1.6820x; 1.6820x over previous
//
#include <hip/hip_runtime.h>

#define B_TOT 4096
#define S_LEN 2048
#define K_CH  32                 // chunks per sequence (must be 32: b = tid>>5)
#define L_CH  64                 // S_LEN / K_CH
#define U_ROW (S_LEN + 8)        // 2056 floats
#define O_ROW (S_LEN + 9)        // 2057 floats
#define SLOT  12                 // floats per (b,chunk) ws slot, 48B -> float4-aligned

// Phase 1 (FINAL=0): per (b,chunk) run d-recurrence from zero state over L_CH
// steps; store final 8-state p_k and d-sum ps_k (== x since x starts at 0).
// Phase 3 (FINAL=1): same recurrence from the true incoming (s,x) written by
// the combine pass; write the outputs.
// Whole 72-float u window loaded upfront (18 float4 in flight -> latency piped).
template<int FINAL>
__global__ __launch_bounds__(256) void arix_chunk(
    const float* __restrict__ u, const float* __restrict__ W,
    float* __restrict__ ws, float* __restrict__ out)
{
    const int tid = blockIdx.x * 256 + threadIdx.x;
    const int k = tid & (K_CH - 1);
    const int b = tid >> 5;

    float wd[8], wu[8];
#pragma unroll
    for (int j = 0; j < 8; ++j) { wd[j] = W[j]; wu[j] = W[8 + j]; }

    const int t0 = k * L_CH;
    const float* ub = u + (long)b * U_ROW + t0;   // 16B-aligned (2056%4==0, t0%4==0)

    float ua[72];
    {
        const float4* up = (const float4*)ub;
#pragma unroll
        for (int q = 0; q < 18; ++q) {
            float4 v = up[q];
            ua[4*q] = v.x; ua[4*q+1] = v.y; ua[4*q+2] = v.z; ua[4*q+3] = v.w;
        }
    }

    float* slot = ws + (size_t)tid * SLOT;   // tid == b*K_CH + k
    float dr[8];
    float x;
    if (FINAL) {
        float4 d0 = ((const float4*)slot)[0];
        float4 d1 = ((const float4*)slot)[1];
        dr[0]=d0.x; dr[1]=d0.y; dr[2]=d0.z; dr[3]=d0.w;
        dr[4]=d1.x; dr[5]=d1.y; dr[6]=d1.z; dr[7]=d1.w;
        x = slot[8];
    } else {
#pragma unroll
        for (int j = 0; j < 8; ++j) dr[j] = 0.f;
        x = 0.f;
    }

    float* ob = out + (long)b * O_ROW + 9 + t0;

#pragma unroll
    for (int s = 0; s < L_CH; ++s) {
        float acc = wu[0] * ua[s + 1];
#pragma unroll
        for (int j = 1; j < 8; ++j) acc = fmaf(wu[j], ua[s + 1 + j], acc);
#pragma unroll
        for (int j = 0; j < 8; ++j) acc = fmaf(wd[j], dr[j], acc);   // dep (j=7) last
#pragma unroll
        for (int j = 0; j < 7; ++j) dr[j] = dr[j + 1];               // reg renaming
        dr[7] = acc;
        x += acc;
        if (FINAL) ob[s] = x;
    }

    if (!FINAL) {
        ((float4*)slot)[0] = make_float4(dr[0], dr[1], dr[2], dr[3]);
        ((float4*)slot)[1] = make_float4(dr[4], dr[5], dr[6], dr[7]);
        slot[8] = x;
    }
}

// Combine: per block, lanes 0..7 build T = A^L (columns) and sumG in LDS from W
// (unit-state homogeneous responses). Then one thread per batch runs the
// K_CH-step serial chunk scan, writing each chunk's true incoming (s, x)
// in-place over (p_k, ps_k). Also writes the 9-float output head.
__global__ __launch_bounds__(256) void arix_combine(
    const float* __restrict__ y, const float* __restrict__ W,
    float* __restrict__ ws, float* __restrict__ out)
{
    __shared__ float Tsh[72];   // [j*9 + i]: column j of T (i<8), sumG[j] at i=8
    const int lt = threadIdx.x;
    if (lt < 8) {
        float wd[8];
#pragma unroll
        for (int i = 0; i < 8; ++i) wd[i] = W[i];
        float dr[8];
#pragma unroll
        for (int i = 0; i < 8; ++i) dr[i] = (i == lt) ? 1.f : 0.f;
        float xs = 0.f;
        for (int t = 0; t < L_CH; ++t) {
            float acc = wd[0] * dr[0];
#pragma unroll
            for (int i = 1; i < 8; ++i) acc = fmaf(wd[i], dr[i], acc);
#pragma unroll
            for (int i = 0; i < 7; ++i) dr[i] = dr[i + 1];
            dr[7] = acc; xs += acc;
        }
#pragma unroll
        for (int i = 0; i < 8; ++i) Tsh[lt*9 + i] = dr[i];
        Tsh[lt*9 + 8] = xs;
    }
    __syncthreads();

    float Tc[8][8], sg[8];
#pragma unroll
    for (int j = 0; j < 8; ++j) {
#pragma unroll
        for (int i = 0; i < 8; ++i) Tc[j][i] = Tsh[j*9 + i];
        sg[j] = Tsh[j*9 + 8];
    }

    const int b = blockIdx.x * 256 + threadIdx.x;
    const float* yb = y + b * 9;
    float* ob = out + (long)b * O_ROW;
    float yv[9];
#pragma unroll
    for (int j = 0; j < 9; ++j) { yv[j] = yb[j]; ob[j] = yv[j]; }
    float s[8];
#pragma unroll
    for (int j = 0; j < 8; ++j) s[j] = yv[j + 1] - yv[j];
    float x = yv[8];

    float* slot = ws + (size_t)b * K_CH * SLOT;
    for (int k = 0; k < K_CH; ++k, slot += SLOT) {
        float p[9];
#pragma unroll
        for (int i = 0; i < 9; ++i) p[i] = slot[i];
        // overwrite slot with this chunk's true incoming state
#pragma unroll
        for (int i = 0; i < 8; ++i) slot[i] = s[i];
        slot[8] = x;
        // advance: s <- T*s + p ;  x <- x + sumG.s + ps
        float ns[8];
#pragma unroll
        for (int i = 0; i < 8; ++i) ns[i] = p[i];
#pragma unroll
        for (int j = 0; j < 8; ++j) {
#pragma unroll
            for (int i = 0; i < 8; ++i) ns[i] = fmaf(Tc[j][i], s[j], ns[i]);
        }
        x += p[8];
#pragma unroll
        for (int j = 0; j < 8; ++j) x = fmaf(sg[j], s[j], x);
#pragma unroll
        for (int i = 0; i < 8; ++i) s[i] = ns[i];
    }
}

extern "C" void kernel_launch(void* const* d_in, const int* in_sizes, int n_in,
                              void* d_out, int out_size, void* d_ws, size_t ws_size,
                              hipStream_t stream) {
    const float* y = (const float*)d_in[0];
    const float* u = (const float*)d_in[1];
    const float* W = (const float*)d_in[2];
    float* out = (float*)d_out;
    float* ws = (float*)d_ws;

    arix_chunk<0><<<dim3(B_TOT * K_CH / 256), dim3(256), 0, stream>>>(u, W, ws, out);
    arix_combine<<<dim3(B_TOT / 256), dim3(256), 0, stream>>>(y, W, ws, out);
    arix_chunk<1><<<dim3(B_TOT * K_CH / 256), dim3(256), 0, stream>>>(u, W, ws, out);
}

// Round 3
// 121.396 us; speedup vs baseline: 2.2082x; 1.3128x over previous
//
#include <hip/hip_runtime.h>

#define B_TOT 4096
#define S_LEN 2048
#define K_CH  64                  // chunks per sequence
#define L_CH  32                  // steps per chunk (S_LEN / K_CH)
#define N_CK  (B_TOT * K_CH)      // 262144 chunk-threads
#define U_ROW (S_LEN + 8)         // 2056
#define O_ROW (S_LEN + 9)         // 2057
// ws layout: 9 SoA planes of N_CK floats: planes 0..7 = d-state, plane 8 = x.

struct F4s { float a, b, c, d; }; // size 16, align 4 — best-effort wide store

// Phase 1 (FINAL=0): per (b,k) run d-recurrence from zero state over L_CH steps,
// store final state + x-sum into ws planes (coalesced).
// Phase 3 (FINAL=1): same recurrence from true incoming state (from combine),
// write the output trajectory.
template<int FINAL>
__global__ __launch_bounds__(256) void arix_chunk(
    const float* __restrict__ u, const float* __restrict__ W,
    float* __restrict__ ws, float* __restrict__ out)
{
    const int tid = blockIdx.x * 256 + threadIdx.x;
    const int k = tid & (K_CH - 1);
    const int b = tid >> 6;

    float wd[8], wu[8];
#pragma unroll
    for (int j = 0; j < 8; ++j) { wd[j] = W[j]; wu[j] = W[8 + j]; }

    const float* ub = u + (long)b * U_ROW + k * L_CH;  // 16B-aligned

    float ua[L_CH + 8];
    {
        const float4* up = (const float4*)ub;
#pragma unroll
        for (int q = 0; q < (L_CH + 8) / 4; ++q) {
            float4 v = up[q];
            ua[4*q] = v.x; ua[4*q+1] = v.y; ua[4*q+2] = v.z; ua[4*q+3] = v.w;
        }
    }

    float dr[8], x;
    if (FINAL) {
#pragma unroll
        for (int i = 0; i < 8; ++i) dr[i] = ws[i * N_CK + tid];
        x = ws[8 * N_CK + tid];
    } else {
#pragma unroll
        for (int i = 0; i < 8; ++i) dr[i] = 0.f;
        x = 0.f;
    }

    float* ob = out + (long)b * O_ROW + 9 + k * L_CH;

#pragma unroll
    for (int s4 = 0; s4 < L_CH; s4 += 4) {
        float xo[4];
#pragma unroll
        for (int q = 0; q < 4; ++q) {
            const int s = s4 + q;
            float acc = wu[0] * ua[s + 1];
#pragma unroll
            for (int j = 1; j < 8; ++j) acc = fmaf(wu[j], ua[s + 1 + j], acc);
#pragma unroll
            for (int j = 0; j < 8; ++j) acc = fmaf(wd[j], dr[j], acc); // dep last
#pragma unroll
            for (int j = 0; j < 7; ++j) dr[j] = dr[j + 1];
            dr[7] = acc;
            x += acc;
            xo[q] = x;
        }
        if (FINAL) {
            F4s v = { xo[0], xo[1], xo[2], xo[3] };
            *(F4s*)(ob + s4) = v;
        }
    }

    if (!FINAL) {
#pragma unroll
        for (int i = 0; i < 8; ++i) ws[i * N_CK + tid] = dr[i];
        ws[8 * N_CK + tid] = x;
    }
}

// Combine: one 64-lane wave per batch, lane k <-> chunk k. Kogge-Stone scan of
// affine chunk maps. Shared per-level linear parts M_l = (A^L)^(2^l) and x-rows
// C_l built per block in LDS (unit responses + repeated squaring).
__global__ __launch_bounds__(256) void arix_combine(
    const float* __restrict__ y, const float* __restrict__ W,
    float* __restrict__ ws, float* __restrict__ out)
{
    __shared__ float Msh[6 * 64];  // level l: M_l[i][j] at Msh[l*64 + i*8 + j]
    __shared__ float Csh[6 * 8];   // level l: C_l[j]
    const int lt = threadIdx.x;

    // level 0: columns of T = A^L and sumG via unit-state responses
    if (lt < 8) {
        float wd[8];
#pragma unroll
        for (int i = 0; i < 8; ++i) wd[i] = W[i];
        float dr[8];
#pragma unroll
        for (int i = 0; i < 8; ++i) dr[i] = (i == lt) ? 1.f : 0.f;
        float xs = 0.f;
        for (int t = 0; t < L_CH; ++t) {
            float acc = wd[0] * dr[0];
#pragma unroll
            for (int i = 1; i < 8; ++i) acc = fmaf(wd[i], dr[i], acc);
#pragma unroll
            for (int i = 0; i < 7; ++i) dr[i] = dr[i + 1];
            dr[7] = acc; xs += acc;
        }
#pragma unroll
        for (int i = 0; i < 8; ++i) Msh[i * 8 + lt] = dr[i];  // column lt
        Csh[lt] = xs;
    }
    __syncthreads();

    // levels 1..5: M_l = M_{l-1}^2 ; C_l = C_{l-1} + C_{l-1} * M_{l-1}
    for (int l = 1; l < 6; ++l) {
        const float* Mp = Msh + (l - 1) * 64;
        const float* Cp = Csh + (l - 1) * 8;
        float mv = 0.f, cv = 0.f;
        if (lt < 64) {
            const int i = lt >> 3, j = lt & 7;
            float a = 0.f;
#pragma unroll
            for (int m = 0; m < 8; ++m) a = fmaf(Mp[i * 8 + m], Mp[m * 8 + j], a);
            mv = a;
        }
        if (lt < 8) {
            float a = Cp[lt];
#pragma unroll
            for (int i = 0; i < 8; ++i) a = fmaf(Cp[i], Mp[i * 8 + lt], a);
            cv = a;
        }
        __syncthreads();
        if (lt < 64) Msh[l * 64 + lt] = mv;
        if (lt < 8)  Csh[l * 8 + lt] = cv;
        __syncthreads();
    }

    const int tid = blockIdx.x * 256 + lt;
    const int k = lt & 63;          // lane id == chunk id (wave <-> batch)
    const int b = tid >> 6;

    float P[8], Q;
#pragma unroll
    for (int i = 0; i < 8; ++i) P[i] = ws[i * N_CK + tid];
    Q = ws[8 * N_CK + tid];

    const float* yb = y + b * 9;
    float yv[9];
#pragma unroll
    for (int i = 0; i < 9; ++i) yv[i] = yb[i];
    float s0[8];
#pragma unroll
    for (int i = 0; i < 8; ++i) s0[i] = yv[i + 1] - yv[i];
    const float x0 = yv[8];

    // fold true initial state into lane 0 (chunk 0's map applied to s0)
    if (k == 0) {
        float np[8];
#pragma unroll
        for (int i = 0; i < 8; ++i) {
            float a = P[i];
#pragma unroll
            for (int j = 0; j < 8; ++j) a = fmaf(Msh[i * 8 + j], s0[j], a);
            np[i] = a;
        }
        float qa = Q;
#pragma unroll
        for (int j = 0; j < 8; ++j) qa = fmaf(Csh[j], s0[j], qa);
#pragma unroll
        for (int i = 0; i < 8; ++i) P[i] = np[i];
        Q = qa;
    }

    // Kogge-Stone inclusive scan: after level l, lane k holds true (s, x-x0)
    // over chunks [max(0,k-2^(l+1)+1) .. k]
#pragma unroll
    for (int l = 0; l < 6; ++l) {
        const int delta = 1 << l;
        float Pl[8], Ql;
#pragma unroll
        for (int i = 0; i < 8; ++i) Pl[i] = __shfl_up(P[i], delta);
        Ql = __shfl_up(Q, delta);
        if (k >= delta) {
            const float* Mp = Msh + l * 64;
            const float* Cp = Csh + l * 8;
            float np[8];
#pragma unroll
            for (int i = 0; i < 8; ++i) {
                float a = P[i];
#pragma unroll
                for (int j = 0; j < 8; ++j) a = fmaf(Mp[i * 8 + j], Pl[j], a);
                np[i] = a;
            }
            float qa = Q + Ql;
#pragma unroll
            for (int j = 0; j < 8; ++j) qa = fmaf(Cp[j], Pl[j], qa);
#pragma unroll
            for (int i = 0; i < 8; ++i) P[i] = np[i];
            Q = qa;
        }
    }

    // chunk k's true incoming state = lane k-1's inclusive result
    float Pin[8], Qin;
#pragma unroll
    for (int i = 0; i < 8; ++i) Pin[i] = __shfl_up(P[i], 1);
    Qin = __shfl_up(Q, 1);
    if (k == 0) {
#pragma unroll
        for (int i = 0; i < 8; ++i) Pin[i] = s0[i];
        Qin = 0.f;
    }

#pragma unroll
    for (int i = 0; i < 8; ++i) ws[i * N_CK + tid] = Pin[i];
    ws[8 * N_CK + tid] = x0 + Qin;

    if (k < 9) out[(long)b * O_ROW + k] = yv[k];
}

extern "C" void kernel_launch(void* const* d_in, const int* in_sizes, int n_in,
                              void* d_out, int out_size, void* d_ws, size_t ws_size,
                              hipStream_t stream) {
    const float* y = (const float*)d_in[0];
    const float* u = (const float*)d_in[1];
    const float* W = (const float*)d_in[2];
    float* out = (float*)d_out;
    float* ws = (float*)d_ws;

    arix_chunk<0><<<dim3(N_CK / 256), dim3(256), 0, stream>>>(u, W, ws, out);
    arix_combine<<<dim3(N_CK / 256), dim3(256), 0, stream>>>(y, W, ws, out);
    arix_chunk<1><<<dim3(N_CK / 256), dim3(256), 0, stream>>>(u, W, ws, out);
}

// Round 4
// 99.277 us; speedup vs baseline: 2.7002x; 1.2228x over previous
//
#include <hip/hip_runtime.h>

#define B_TOT 4096
#define S_LEN 2048
#define K_CH  64                  // chunks per sequence == wave lanes
#define L_CH  32                  // steps per chunk
#define U_ROW (S_LEN + 8)         // 2056
#define O_ROW (S_LEN + 9)         // 2057

struct F4s { float a, b, c, d; }; // size 16, align 4 — best-effort wide store

// One wave per batch. Lane k owns chunk k.
// Phase 1: run d-recurrence from zero state (u window held in registers).
// Phase 2: Kogge-Stone scan of affine chunk maps across the wave; level
//          matrices M_l=(A^L)^(2^l) and x-rows C_l built per block in LDS.
// Phase 3: re-run recurrence from true incoming state, write outputs.
__global__ __launch_bounds__(256) void arix_fused(
    const float* __restrict__ y, const float* __restrict__ u,
    const float* __restrict__ W, float* __restrict__ out)
{
    __shared__ float Msh[6 * 64];  // level l: M_l[i][j] at Msh[l*64+i*8+j]
    __shared__ float Csh[6 * 8];
    const int lt = threadIdx.x;
    const int k  = lt & 63;                 // lane == chunk id
    const int b  = blockIdx.x * 4 + (lt >> 6);  // wave == batch

    float wd[8], wu[8];
#pragma unroll
    for (int j = 0; j < 8; ++j) { wd[j] = W[j]; wu[j] = W[8 + j]; }

    // Issue u loads FIRST so they are in flight during the M-build.
    const float* ub = u + (long)b * U_ROW + k * L_CH;  // 16B-aligned
    float ua[L_CH + 8];
    {
        const float4* up = (const float4*)ub;
#pragma unroll
        for (int q = 0; q < (L_CH + 8) / 4; ++q) {
            float4 v = up[q];
            ua[4*q] = v.x; ua[4*q+1] = v.y; ua[4*q+2] = v.z; ua[4*q+3] = v.w;
        }
    }
    // y row (wave-uniform address -> broadcast load)
    const float* yb = y + b * 9;
    float yv[9];
#pragma unroll
    for (int i = 0; i < 9; ++i) yv[i] = yb[i];

    // ---- build level-0 map T=A^L (columns) + sumG via unit responses ----
    if (lt < 8) {
        float dr[8];
#pragma unroll
        for (int i = 0; i < 8; ++i) dr[i] = (i == lt) ? 1.f : 0.f;
        float xs = 0.f;
        for (int t = 0; t < L_CH; ++t) {
            float acc = wd[0] * dr[0];
#pragma unroll
            for (int i = 1; i < 8; ++i) acc = fmaf(wd[i], dr[i], acc);
#pragma unroll
            for (int i = 0; i < 7; ++i) dr[i] = dr[i + 1];
            dr[7] = acc; xs += acc;
        }
#pragma unroll
        for (int i = 0; i < 8; ++i) Msh[i * 8 + lt] = dr[i];  // column lt
        Csh[lt] = xs;
    }
    __syncthreads();
    // levels 1..5: M_l = M_{l-1}^2 ; C_l = C_{l-1} + C_{l-1}*M_{l-1}
    for (int l = 1; l < 6; ++l) {
        const float* Mp = Msh + (l - 1) * 64;
        const float* Cp = Csh + (l - 1) * 8;
        float mv = 0.f, cv = 0.f;
        if (lt < 64) {
            const int i = lt >> 3, j = lt & 7;
            float a = 0.f;
#pragma unroll
            for (int m = 0; m < 8; ++m) a = fmaf(Mp[i * 8 + m], Mp[m * 8 + j], a);
            mv = a;
        }
        if (lt < 8) {
            float a = Cp[lt];
#pragma unroll
            for (int i = 0; i < 8; ++i) a = fmaf(Cp[i], Mp[i * 8 + lt], a);
            cv = a;
        }
        __syncthreads();
        if (lt < 64) Msh[l * 64 + lt] = mv;
        if (lt < 8)  Csh[l * 8 + lt] = cv;
        __syncthreads();
    }

    // ---- phase 1: zero-state chunk recurrence ----
    float dr[8], x = 0.f;
#pragma unroll
    for (int i = 0; i < 8; ++i) dr[i] = 0.f;
#pragma unroll
    for (int s = 0; s < L_CH; ++s) {
        float acc = wu[0] * ua[s + 1];
#pragma unroll
        for (int j = 1; j < 8; ++j) acc = fmaf(wu[j], ua[s + 1 + j], acc);
#pragma unroll
        for (int j = 0; j < 8; ++j) acc = fmaf(wd[j], dr[j], acc);
#pragma unroll
        for (int j = 0; j < 7; ++j) dr[j] = dr[j + 1];
        dr[7] = acc;
        x += acc;
    }

    // ---- phase 2: wave scan of affine maps ----
    float s0[8];
#pragma unroll
    for (int i = 0; i < 8; ++i) s0[i] = yv[i + 1] - yv[i];
    const float x0 = yv[8];

    float P[8], Q = x;
#pragma unroll
    for (int i = 0; i < 8; ++i) P[i] = dr[i];

    if (k == 0) {   // fold true initial state into chunk 0's result
        float np[8];
#pragma unroll
        for (int i = 0; i < 8; ++i) {
            float a = P[i];
#pragma unroll
            for (int j = 0; j < 8; ++j) a = fmaf(Msh[i * 8 + j], s0[j], a);
            np[i] = a;
        }
        float qa = Q;
#pragma unroll
        for (int j = 0; j < 8; ++j) qa = fmaf(Csh[j], s0[j], qa);
#pragma unroll
        for (int i = 0; i < 8; ++i) P[i] = np[i];
        Q = qa;
    }

#pragma unroll
    for (int l = 0; l < 6; ++l) {
        const int delta = 1 << l;
        float Pl[8], Ql;
#pragma unroll
        for (int i = 0; i < 8; ++i) Pl[i] = __shfl_up(P[i], delta);
        Ql = __shfl_up(Q, delta);
        if (k >= delta) {
            const float* Mp = Msh + l * 64;
            const float* Cp = Csh + l * 8;
            float np[8];
#pragma unroll
            for (int i = 0; i < 8; ++i) {
                float a = P[i];
#pragma unroll
                for (int j = 0; j < 8; ++j) a = fmaf(Mp[i * 8 + j], Pl[j], a);
                np[i] = a;
            }
            float qa = Q + Ql;
#pragma unroll
            for (int j = 0; j < 8; ++j) qa = fmaf(Cp[j], Pl[j], qa);
#pragma unroll
            for (int i = 0; i < 8; ++i) P[i] = np[i];
            Q = qa;
        }
    }

    // incoming state of chunk k = inclusive result of lane k-1
    float Pin[8], Qin;
#pragma unroll
    for (int i = 0; i < 8; ++i) Pin[i] = __shfl_up(P[i], 1);
    Qin = __shfl_up(Q, 1);
    if (k == 0) {
#pragma unroll
        for (int i = 0; i < 8; ++i) Pin[i] = s0[i];
        Qin = 0.f;
    }

    // ---- phase 3: true recurrence, write outputs (u still in registers) ----
#pragma unroll
    for (int i = 0; i < 8; ++i) dr[i] = Pin[i];
    x = x0 + Qin;

    float* ob = out + (long)b * O_ROW + 9 + k * L_CH;
#pragma unroll
    for (int s4 = 0; s4 < L_CH; s4 += 4) {
        float xo[4];
#pragma unroll
        for (int q = 0; q < 4; ++q) {
            const int s = s4 + q;
            float acc = wu[0] * ua[s + 1];
#pragma unroll
            for (int j = 1; j < 8; ++j) acc = fmaf(wu[j], ua[s + 1 + j], acc);
#pragma unroll
            for (int j = 0; j < 8; ++j) acc = fmaf(wd[j], dr[j], acc);
#pragma unroll
            for (int j = 0; j < 7; ++j) dr[j] = dr[j + 1];
            dr[7] = acc;
            x += acc;
            xo[q] = x;
        }
        F4s v = { xo[0], xo[1], xo[2], xo[3] };
        *(F4s*)(ob + s4) = v;
    }

    if (k < 9) out[(long)b * O_ROW + k] = yv[k];
}

extern "C" void kernel_launch(void* const* d_in, const int* in_sizes, int n_in,
                              void* d_out, int out_size, void* d_ws, size_t ws_size,
                              hipStream_t stream) {
    const float* y = (const float*)d_in[0];
    const float* u = (const float*)d_in[1];
    const float* W = (const float*)d_in[2];
    float* out = (float*)d_out;

    arix_fused<<<dim3(B_TOT / 4), dim3(256), 0, stream>>>(y, u, W, out);
}